// Round 8
// baseline (83.458 us; speedup 1.0000x reference)
//
#include <hip/hip_runtime.h>

// Problem constants (from reference)
#define B        8192
#define N_IN     8
#define N_MFS    4
#define N_RULES  2048

#define THREADS  256
#define NB       8                    // batches per block
#define RSPLIT   2                    // rule groups: grid = (B/NB)*RSPLIT = 2048 blocks
#define RPB      (N_RULES / RSPLIT)   // 1024 rules/block -> 4 rules/thread
#define RPT      4
#define LUT_W    101                  // words per batch pair-LUT (100 used + 1 pad)
#define XS_W     (N_IN * N_MFS)       // 32 floats per batch

typedef float vfloat4 __attribute__((ext_vector_type(4)));

// R14 == R13 resubmitted verbatim: R13's bench died on container
// acquisition ("MI355X container failed twice"), same infra signature as
// R9 (which then passed unchanged on resubmit). Source audited: bounds
// legal, stores 16B-aligned, 4.2KB LDS, no device sync. A/B preserved.
//
// R13: complete the NT store-width ladder at full occupancy.
//  Post-mortem R12: halving gather instrs REGRESSED (83.1 vs 79.9) ->
//  main-loop instruction count is NOT the limiter; interleaved layout
//  abandoned, rest-major broadcast gather restored (counter-verified 0
//  conflicts). Ledger of wins: NT stores, 2048 blocks = 32 waves/CU,
//  fewer/wider stores (4B 80.9 -> 8B 79.9), lower LUT redundancy.
//  This round extrapolates exactly those: 16B NT at 32 waves/CU (never
//  measured; R6's 16B-NT ran at 8 waves/CU).
//  - NB=8, RSPLIT=2, 4 rules/thread: one float4 NT store per batch
//    (store instrs halved vs R11), LUT build 1.6M entries device-wide
//    (halved vs R11), grid (2,1024) = 2048 blocks = 8/CU = 32 waves/CU.
//  - LDS 4.2 KB/block; gather = 16 broadcast ds_read_b32/batch within
//    25-word windows (same-bank => same-word => free broadcast).
//  Pre-commitment: >=79.5 -> ladder complete, declare roofline next
//  round (45us mandatory poison fill + fixed overhead + kernel at its
//  write floor).
__global__ __launch_bounds__(THREADS, 8) void fire_kernel(
        const float* __restrict__ x,
        const int*   __restrict__ mf,
        float* __restrict__ out)
{
    __shared__ float xs[NB * XS_W];      // 1 KB: 8 batches x 32 floats
    __shared__ float slut[NB * LUT_W];   // 3.2 KB: 8 batches x 101 words

    const int tid = threadIdx.x;
    const int rg  = blockIdx.x;              // rule group 0..1
    const int bg  = blockIdx.y;              // batch group 0..1023
    const int b0  = bg * NB;
    const int r0  = rg * RPB + tid * RPT;    // this thread's 4 consecutive rules

    // ---- Stage this block's x slice: 256 floats = 64 x float4, coalesced.
    if (tid < (NB * XS_W) / 4) {
        ((float4*)xs)[tid] = ((const float4*)(x + (size_t)b0 * XS_W))[tid];
    }

    // ---- Pack this thread's 4 rules into 16 register word offsets.
    int woff[RPT][4];
#pragma unroll
    for (int j = 0; j < RPT; ++j) {
        const int4* mr = (const int4*)(mf + (size_t)(r0 + j) * N_IN);
        const int4 lo = mr[0];
        const int4 hi = mr[1];
        const int idx[8] = {lo.x, lo.y, lo.z, lo.w, hi.x, hi.y, hi.z, hi.w};
#pragma unroll
        for (int p = 0; p < 4; ++p) {
            const int a = idx[2*p]   < 0 ? 4 : idx[2*p];
            const int b = idx[2*p+1] < 0 ? 4 : idx[2*p+1];
            woff[j][p] = p * 25 + a * 5 + b;     // 0..99
        }
    }
    __syncthreads();   // xs ready

    // ---- Build pair-product LUTs from LDS-resident x (800 entries,
    //      256 threads -> ~3 iters): slut[bl*101 + p*25+a*5+b] = va*vb.
    for (int e = tid; e < NB * 100; e += THREADS) {
        const int bl   = e / 100;
        const int rest = e - bl * 100;
        const int p    = rest / 25;
        const int c    = rest - p * 25;
        const int a    = c / 5;
        const int bb   = c - a * 5;
        const float* xb = xs + bl * XS_W;
        const float va = (a  < 4) ? xb[(2*p)   * N_MFS + a ] : 1.0f;
        const float vb = (bb < 4) ? xb[(2*p+1) * N_MFS + bb] : 1.0f;
        slut[bl * LUT_W + rest] = va * vb;
    }
    __syncthreads();   // slut ready

    // ---- Main loop: per batch, 16 broadcast ds_read_b32 (imm batch
    //      offsets) + 12 muls + ONE 16B NT store (wave = 1KB contiguous).
    float* o = out + (size_t)b0 * N_RULES + rg * RPB + tid * RPT;
#pragma unroll 2
    for (int bl = 0; bl < NB; ++bl) {
        const float* lb = slut + bl * LUT_W;
        vfloat4 res;
        {
            const float v0 = lb[woff[0][0]], v1 = lb[woff[0][1]];
            const float v2 = lb[woff[0][2]], v3 = lb[woff[0][3]];
            res.x = (v0 * v1) * (v2 * v3);
        }
        {
            const float v0 = lb[woff[1][0]], v1 = lb[woff[1][1]];
            const float v2 = lb[woff[1][2]], v3 = lb[woff[1][3]];
            res.y = (v0 * v1) * (v2 * v3);
        }
        {
            const float v0 = lb[woff[2][0]], v1 = lb[woff[2][1]];
            const float v2 = lb[woff[2][2]], v3 = lb[woff[2][3]];
            res.z = (v0 * v1) * (v2 * v3);
        }
        {
            const float v0 = lb[woff[3][0]], v1 = lb[woff[3][1]];
            const float v2 = lb[woff[3][2]], v3 = lb[woff[3][3]];
            res.w = (v0 * v1) * (v2 * v3);
        }
        __builtin_nontemporal_store(res, (vfloat4*)(o + (size_t)bl * N_RULES));
    }
}

extern "C" void kernel_launch(void* const* d_in, const int* in_sizes, int n_in,
                              void* d_out, int out_size, void* d_ws, size_t ws_size,
                              hipStream_t stream) {
    const float* x  = (const float*)d_in[0];   // (B, N_IN, N_MFS) fp32
    const int*   mf = (const int*)d_in[1];     // (N_RULES, N_IN) int32
    float* out = (float*)d_out;                // (B, N_RULES) fp32
    (void)d_ws; (void)ws_size;

    dim3 grid(RSPLIT, B / NB);
    fire_kernel<<<grid, THREADS, 0, stream>>>(x, mf, out);
}